// Round 1
// baseline (585.753 us; speedup 1.0000x reference)
//
#include <hip/hip_runtime.h>
#include <hip/hip_bf16.h>

// ---------------------------------------------------------------------------
// GCN: 3 x { h = A_norm (x W) + b ; relu } -> mean-pool by graph -> linear
// N=50000 nodes, E=800000 edges, C=128 channels, G=512 graphs, OUT=12
// All f32 (tolerance too tight for bf16). CSR built per launch via counting
// sort; aggregation is one wave per node (no float atomics in hot path).
// ---------------------------------------------------------------------------

#define CH 128   // channels (IN == HID)

// ---- degree (in-degree, excluding self loop) ------------------------------
__global__ void k_deg(const int* __restrict__ dst, int* __restrict__ cnt, int E) {
    int e = blockIdx.x * blockDim.x + threadIdx.x;
    if (e < E) atomicAdd(&cnt[dst[e]], 1);
}

// ---- dinv[v] = 1/sqrt(indeg+1) --------------------------------------------
__global__ void k_dinv(const int* __restrict__ cnt, float* __restrict__ dinv, int n) {
    int v = blockIdx.x * blockDim.x + threadIdx.x;
    if (v < n) dinv[v] = 1.0f / sqrtf((float)(cnt[v] + 1));
}

// ---- single-block exclusive scan of cnt[0..n) -> rowptr[0..n] -------------
__global__ __launch_bounds__(1024) void k_scan(const int* __restrict__ cnt,
                                               int* __restrict__ rowptr, int n) {
    __shared__ int wave_tot[16];
    __shared__ int chunk_base;
    int tid = threadIdx.x;
    int lane = tid & 63;
    int wid = tid >> 6;
    if (tid == 0) chunk_base = 0;
    __syncthreads();
    const int CHUNK = 4096;  // 1024 threads * 4 elems
    for (int base = 0; base < n; base += CHUNK) {
        int idx0 = base + tid * 4;
        int v0 = (idx0 + 0 < n) ? cnt[idx0 + 0] : 0;
        int v1 = (idx0 + 1 < n) ? cnt[idx0 + 1] : 0;
        int v2 = (idx0 + 2 < n) ? cnt[idx0 + 2] : 0;
        int v3 = (idx0 + 3 < n) ? cnt[idx0 + 3] : 0;
        int local = v0 + v1 + v2 + v3;
        // inclusive wave scan of local
        int s = local;
        #pragma unroll
        for (int off = 1; off < 64; off <<= 1) {
            int t = __shfl_up(s, off, 64);
            if (lane >= off) s += t;
        }
        if (lane == 63) wave_tot[wid] = s;
        __syncthreads();
        int wbase = 0;
        for (int w = 0; w < wid; ++w) wbase += wave_tot[w];
        int excl = chunk_base + wbase + (s - local);
        if (idx0 + 0 < n) rowptr[idx0 + 0] = excl;  excl += v0;
        if (idx0 + 1 < n) rowptr[idx0 + 1] = excl;  excl += v1;
        if (idx0 + 2 < n) rowptr[idx0 + 2] = excl;  excl += v2;
        if (idx0 + 3 < n) rowptr[idx0 + 3] = excl;
        __syncthreads();
        if (tid == 1023) chunk_base += wbase + s;
        __syncthreads();
    }
    if (tid == 0) rowptr[n] = chunk_base;
}

// ---- scatter edges into CSR slots -----------------------------------------
__global__ void k_scatter(const int* __restrict__ src, const int* __restrict__ dst,
                          const float* __restrict__ dinv, const int* __restrict__ rowptr,
                          int* __restrict__ cursor, int* __restrict__ csr_src,
                          float* __restrict__ csr_w, int E) {
    int e = blockIdx.x * blockDim.x + threadIdx.x;
    if (e >= E) return;
    int s = src[e], d = dst[e];
    int pos = rowptr[d] + atomicAdd(&cursor[d], 1);
    csr_src[pos] = s;
    csr_w[pos] = dinv[s] * dinv[d];
}

// ---- GEMM: C[M][128] = A[M][128] @ W[128][128]  (f32 vector ALU) ----------
__global__ __launch_bounds__(256) void k_gemm(const float* __restrict__ A,
                                              const float* __restrict__ W,
                                              float* __restrict__ C, int M) {
    __shared__ float As[64][32];
    __shared__ float Bs[32][128];
    int tid = threadIdx.x;
    int tcol = tid & 31;   // 32 col-groups of 4 cols
    int trow = tid >> 5;   // 8 row-groups; rows trow + i*8
    int row0 = blockIdx.x * 64;
    float acc[8][4] = {};
    for (int kk = 0; kk < CH; kk += 32) {
        #pragma unroll
        for (int l = 0; l < 2; ++l) {
            int idx = tid * 2 + l;          // 0..511  (64x32 = 512 float4)
            int r = idx >> 3;
            int kp = (idx & 7) * 4;
            int grow = row0 + r;
            float4 val = (grow < M) ? *(const float4*)&A[(size_t)grow * CH + kk + kp]
                                    : make_float4(0.f, 0.f, 0.f, 0.f);
            *(float4*)&As[r][kp] = val;
        }
        #pragma unroll
        for (int l = 0; l < 4; ++l) {
            int idx = tid * 4 + l;          // 0..1023 (32x128 = 1024 float4)
            int r = idx >> 5;
            int cp = (idx & 31) * 4;
            *(float4*)&Bs[r][cp] = *(const float4*)&W[(size_t)(kk + r) * CH + cp];
        }
        __syncthreads();
        #pragma unroll
        for (int k = 0; k < 32; ++k) {
            float4 b = *(const float4*)&Bs[k][tcol * 4];
            #pragma unroll
            for (int i = 0; i < 8; ++i) {
                float a = As[trow + i * 8][k];
                acc[i][0] += a * b.x; acc[i][1] += a * b.y;
                acc[i][2] += a * b.z; acc[i][3] += a * b.w;
            }
        }
        __syncthreads();
    }
    #pragma unroll
    for (int i = 0; i < 8; ++i) {
        int grow = row0 + trow + i * 8;
        if (grow < M) *(float4*)&C[(size_t)grow * CH + tcol * 4] = *(float4*)&acc[i][0];
    }
}

// ---- aggregation: out[v] = dinv[v]^2*T[v] + sum_in csr_w*T[src] + b (,relu)
__global__ __launch_bounds__(256) void k_agg(const float* __restrict__ T,
                                             const int* __restrict__ rowptr,
                                             const int* __restrict__ csr_src,
                                             const float* __restrict__ csr_w,
                                             const float* __restrict__ dinv,
                                             const float* __restrict__ bias,
                                             float* __restrict__ out,
                                             int n, int do_relu) {
    int wid = threadIdx.x >> 6;
    int lane = threadIdx.x & 63;
    int v = blockIdx.x * 4 + wid;
    if (v >= n) return;
    int c = lane * 2;
    float di = dinv[v];
    float2 acc = *(const float2*)&T[(size_t)v * CH + c];
    float dd = di * di;
    acc.x *= dd; acc.y *= dd;
    int beg = rowptr[v], end = rowptr[v + 1];
    for (int p = beg; p < end; ++p) {
        int s = csr_src[p];          // wave-uniform load (broadcast)
        float w = csr_w[p];
        float2 hv = *(const float2*)&T[(size_t)s * CH + c];
        acc.x += w * hv.x;
        acc.y += w * hv.y;
    }
    float2 bb = *(const float2*)&bias[c];
    acc.x += bb.x; acc.y += bb.y;
    if (do_relu) { acc.x = fmaxf(acc.x, 0.f); acc.y = fmaxf(acc.y, 0.f); }
    *(float2*)&out[(size_t)v * CH + c] = acc;
}

// ---- pooling: atomic add node rows into per-graph sums --------------------
__global__ __launch_bounds__(256) void k_pool(const float* __restrict__ h,
                                              const int* __restrict__ batch,
                                              float* __restrict__ pool,
                                              int* __restrict__ pcnt, int n) {
    int wid = threadIdx.x >> 6;
    int lane = threadIdx.x & 63;
    int v = blockIdx.x * 4 + wid;
    if (v >= n) return;
    int g = batch[v];
    int c = lane * 2;
    float2 hv = *(const float2*)&h[(size_t)v * CH + c];
    atomicAdd(&pool[g * CH + c], hv.x);
    atomicAdd(&pool[g * CH + c + 1], hv.y);
    if (lane == 0) atomicAdd(&pcnt[g], 1);
}

// ---- classifier: out[g][j] = dot(pool[g]/cnt, Wc[:,j]) + bc[j] ------------
__global__ __launch_bounds__(128) void k_cls(const float* __restrict__ pool,
                                             const int* __restrict__ pcnt,
                                             const float* __restrict__ Wc,
                                             const float* __restrict__ bc,
                                             float* __restrict__ out, int OUT) {
    __shared__ float p[CH];
    int g = blockIdx.x;
    float cnt = fmaxf((float)pcnt[g], 1.0f);
    p[threadIdx.x] = pool[g * CH + threadIdx.x] / cnt;
    __syncthreads();
    if (threadIdx.x < OUT) {
        float s = bc[threadIdx.x];
        for (int k = 0; k < CH; ++k) s += p[k] * Wc[k * OUT + threadIdx.x];
        out[g * OUT + threadIdx.x] = s;
    }
}

extern "C" void kernel_launch(void* const* d_in, const int* in_sizes, int n_in,
                              void* d_out, int out_size, void* d_ws, size_t ws_size,
                              hipStream_t stream) {
    const float* x     = (const float*)d_in[0];
    const int*   eidx  = (const int*)d_in[1];
    const int*   batch = (const int*)d_in[2];
    const float* W0 = (const float*)d_in[3];
    const float* b0 = (const float*)d_in[4];
    const float* W1 = (const float*)d_in[5];
    const float* b1 = (const float*)d_in[6];
    const float* W2 = (const float*)d_in[7];
    const float* b2 = (const float*)d_in[8];
    const float* Wc = (const float*)d_in[9];
    const float* bc = (const float*)d_in[10];
    float* out = (float*)d_out;

    const int n = in_sizes[0] / CH;        // 50000
    const int E = in_sizes[1] / 2;         // 800000
    const int OUT = 12;
    const int G = out_size / OUT;          // 512
    const int* src = eidx;
    const int* dst = eidx + E;

    // ---- workspace carve-up (256B aligned) ----
    char* ws = (char*)d_ws;
    size_t off = 0;
    auto carve = [&](size_t bytes) -> char* {
        off = (off + 255) & ~(size_t)255;
        char* p = ws + off;
        off += bytes;
        return p;
    };
    int*   cnt     = (int*)carve((size_t)2 * n * 4);   // cnt[n] + cursor[n] contiguous
    int*   cursor  = cnt + n;
    int*   rowptr  = (int*)carve((size_t)(n + 1) * 4);
    float* dinv    = (float*)carve((size_t)n * 4);
    int*   csr_src = (int*)carve((size_t)E * 4);
    float* csr_w   = (float*)carve((size_t)E * 4);
    float* pool    = (float*)carve((size_t)(G * CH + G) * 4);  // pool + pcnt contiguous
    int*   pcnt    = (int*)(pool + G * CH);
    float* T    = (float*)carve((size_t)n * CH * 4);
    float* bufA = (float*)carve((size_t)n * CH * 4);
    float* bufB = (float*)carve((size_t)n * CH * 4);
    (void)ws_size;

    // ---- zero the accumulators used this launch ----
    hipMemsetAsync(cnt, 0, (size_t)2 * n * 4, stream);
    hipMemsetAsync(pool, 0, (size_t)(G * CH + G) * 4, stream);

    // ---- graph preprocessing: degree -> dinv -> rowptr -> CSR ----
    k_deg<<<(E + 255) / 256, 256, 0, stream>>>(dst, cnt, E);
    k_dinv<<<(n + 255) / 256, 256, 0, stream>>>(cnt, dinv, n);
    k_scan<<<1, 1024, 0, stream>>>(cnt, rowptr, n);
    k_scatter<<<(E + 255) / 256, 256, 0, stream>>>(src, dst, dinv, rowptr, cursor,
                                                   csr_src, csr_w, E);

    const int gemm_grid = (n + 63) / 64;
    const int agg_grid  = (n + 3) / 4;

    // ---- layer 0: x -> bufB ----
    k_gemm<<<gemm_grid, 256, 0, stream>>>(x, W0, T, n);
    k_agg<<<agg_grid, 256, 0, stream>>>(T, rowptr, csr_src, csr_w, dinv, b0, bufB, n, 1);
    // ---- layer 1: bufB -> bufA ----
    k_gemm<<<gemm_grid, 256, 0, stream>>>(bufB, W1, T, n);
    k_agg<<<agg_grid, 256, 0, stream>>>(T, rowptr, csr_src, csr_w, dinv, b1, bufA, n, 1);
    // ---- layer 2: bufA -> bufB (no relu) ----
    k_gemm<<<gemm_grid, 256, 0, stream>>>(bufA, W2, T, n);
    k_agg<<<agg_grid, 256, 0, stream>>>(T, rowptr, csr_src, csr_w, dinv, b2, bufB, n, 0);

    // ---- pool + classify ----
    k_pool<<<agg_grid, 256, 0, stream>>>(bufB, batch, pool, pcnt, n);
    k_cls<<<G, CH, 0, stream>>>(pool, pcnt, Wc, bc, out, OUT);
}

// Round 2
// 435.586 us; speedup vs baseline: 1.3447x; 1.3447x over previous
//
#include <hip/hip_runtime.h>
#include <hip/hip_bf16.h>

// ---------------------------------------------------------------------------
// GCN: 3 x { h = A_norm (x W) + b ; relu } -> mean-pool by graph -> linear
// N=50000 nodes, E=800000 edges, C=128 channels, G=512 graphs, OUT=12
// All f32 (tolerance too tight for bf16). CSR built per launch via counting
// sort; aggregation one wave per node; pooling via sorted-batch segments
// (no float atomics anywhere in the hot path).
// ---------------------------------------------------------------------------

#define CH 128   // channels (IN == HID)

// ---- degree (in-degree, excluding self loop) ------------------------------
__global__ void k_deg(const int* __restrict__ dst, int* __restrict__ cnt, int E) {
    int e = blockIdx.x * blockDim.x + threadIdx.x;
    if (e < E) atomicAdd(&cnt[dst[e]], 1);
}

// ---- dinv[v] = 1/sqrt(indeg+1) --------------------------------------------
__global__ void k_dinv(const int* __restrict__ cnt, float* __restrict__ dinv, int n) {
    int v = blockIdx.x * blockDim.x + threadIdx.x;
    if (v < n) dinv[v] = 1.0f / sqrtf((float)(cnt[v] + 1));
}

// ---- single-block exclusive scan of cnt[0..n) -> rowptr[0..n] -------------
__global__ __launch_bounds__(1024) void k_scan(const int* __restrict__ cnt,
                                               int* __restrict__ rowptr, int n) {
    __shared__ int wave_tot[16];
    __shared__ int chunk_base;
    int tid = threadIdx.x;
    int lane = tid & 63;
    int wid = tid >> 6;
    if (tid == 0) chunk_base = 0;
    __syncthreads();
    const int CHUNK = 4096;  // 1024 threads * 4 elems
    for (int base = 0; base < n; base += CHUNK) {
        int idx0 = base + tid * 4;
        int v0 = (idx0 + 0 < n) ? cnt[idx0 + 0] : 0;
        int v1 = (idx0 + 1 < n) ? cnt[idx0 + 1] : 0;
        int v2 = (idx0 + 2 < n) ? cnt[idx0 + 2] : 0;
        int v3 = (idx0 + 3 < n) ? cnt[idx0 + 3] : 0;
        int local = v0 + v1 + v2 + v3;
        int s = local;
        #pragma unroll
        for (int off = 1; off < 64; off <<= 1) {
            int t = __shfl_up(s, off, 64);
            if (lane >= off) s += t;
        }
        if (lane == 63) wave_tot[wid] = s;
        __syncthreads();
        int wbase = 0;
        for (int w = 0; w < wid; ++w) wbase += wave_tot[w];
        int excl = chunk_base + wbase + (s - local);
        if (idx0 + 0 < n) rowptr[idx0 + 0] = excl;  excl += v0;
        if (idx0 + 1 < n) rowptr[idx0 + 1] = excl;  excl += v1;
        if (idx0 + 2 < n) rowptr[idx0 + 2] = excl;  excl += v2;
        if (idx0 + 3 < n) rowptr[idx0 + 3] = excl;
        __syncthreads();
        if (tid == 1023) chunk_base += wbase + s;
        __syncthreads();
    }
    if (tid == 0) rowptr[n] = chunk_base;
}

// ---- scatter edges into CSR slots -----------------------------------------
__global__ void k_scatter(const int* __restrict__ src, const int* __restrict__ dst,
                          const float* __restrict__ dinv, const int* __restrict__ rowptr,
                          int* __restrict__ cursor, int* __restrict__ csr_src,
                          float* __restrict__ csr_w, int E) {
    int e = blockIdx.x * blockDim.x + threadIdx.x;
    if (e >= E) return;
    int s = src[e], d = dst[e];
    int pos = rowptr[d] + atomicAdd(&cursor[d], 1);
    csr_src[pos] = s;
    csr_w[pos] = dinv[s] * dinv[d];
}

// ---- graph segment boundaries: gstart[g] = first v with batch[v] >= g -----
__global__ void k_bounds(const int* __restrict__ batch, int* __restrict__ gstart,
                         int n, int G) {
    int v = blockIdx.x * blockDim.x + threadIdx.x;
    if (v > n) return;
    int prev = (v == 0) ? -1 : batch[v - 1];
    int cur  = (v == n) ? G  : batch[v];
    for (int g = prev + 1; g <= cur; ++g) gstart[g] = v;
}

// ---- GEMM: C[M][128] = A[M][128] @ W[128][128]  (f32 vector ALU) ----------
__global__ __launch_bounds__(256) void k_gemm(const float* __restrict__ A,
                                              const float* __restrict__ W,
                                              float* __restrict__ C, int M) {
    __shared__ float As[64][32];
    __shared__ float Bs[32][128];
    int tid = threadIdx.x;
    int tcol = tid & 31;   // 32 col-groups of 4 cols
    int trow = tid >> 5;   // 8 row-groups; rows trow + i*8
    int row0 = blockIdx.x * 64;
    float acc[8][4] = {};
    for (int kk = 0; kk < CH; kk += 32) {
        #pragma unroll
        for (int l = 0; l < 2; ++l) {
            int idx = tid * 2 + l;          // 0..511  (64x32 = 512 float4)
            int r = idx >> 3;
            int kp = (idx & 7) * 4;
            int grow = row0 + r;
            float4 val = (grow < M) ? *(const float4*)&A[(size_t)grow * CH + kk + kp]
                                    : make_float4(0.f, 0.f, 0.f, 0.f);
            *(float4*)&As[r][kp] = val;
        }
        #pragma unroll
        for (int l = 0; l < 4; ++l) {
            int idx = tid * 4 + l;          // 0..1023 (32x128 = 1024 float4)
            int r = idx >> 5;
            int cp = (idx & 31) * 4;
            *(float4*)&Bs[r][cp] = *(const float4*)&W[(size_t)(kk + r) * CH + cp];
        }
        __syncthreads();
        #pragma unroll
        for (int k = 0; k < 32; ++k) {
            float4 b = *(const float4*)&Bs[k][tcol * 4];
            #pragma unroll
            for (int i = 0; i < 8; ++i) {
                float a = As[trow + i * 8][k];
                acc[i][0] += a * b.x; acc[i][1] += a * b.y;
                acc[i][2] += a * b.z; acc[i][3] += a * b.w;
            }
        }
        __syncthreads();
    }
    #pragma unroll
    for (int i = 0; i < 8; ++i) {
        int grow = row0 + trow + i * 8;
        if (grow < M) *(float4*)&C[(size_t)grow * CH + tcol * 4] = *(float4*)&acc[i][0];
    }
}

// ---- aggregation: out[v] = dinv[v]^2*T[v] + sum_in csr_w*T[src] + b (,relu)
// One wave per node; 2 edges/iteration (half-wave each, float4/lane = 16B).
__global__ __launch_bounds__(256) void k_agg(const float* __restrict__ T,
                                             const int* __restrict__ rowptr,
                                             const int* __restrict__ csr_src,
                                             const float* __restrict__ csr_w,
                                             const float* __restrict__ dinv,
                                             const float* __restrict__ bias,
                                             float* __restrict__ out,
                                             int n, int do_relu) {
    int wid = threadIdx.x >> 6;
    int lane = threadIdx.x & 63;
    int v = blockIdx.x * 4 + wid;
    if (v >= n) return;
    int half = lane >> 5;
    int l32 = lane & 31;
    int c = l32 * 4;
    float4 acc = make_float4(0.f, 0.f, 0.f, 0.f);
    int beg = rowptr[v], end = rowptr[v + 1];
    for (int p = beg + half; p < end; p += 2) {
        int s = csr_src[p];          // uniform within half-wave (broadcast)
        float w = csr_w[p];
        float4 hv = *(const float4*)&T[(size_t)s * CH + c];
        acc.x += w * hv.x; acc.y += w * hv.y;
        acc.z += w * hv.z; acc.w += w * hv.w;
    }
    // combine the two half-wave edge streams (lane i <-> lane i^32, same channels)
    acc.x += __shfl_xor(acc.x, 32, 64);
    acc.y += __shfl_xor(acc.y, 32, 64);
    acc.z += __shfl_xor(acc.z, 32, 64);
    acc.w += __shfl_xor(acc.w, 32, 64);
    if (half == 0) {
        float di = dinv[v];
        float dd = di * di;
        float4 sv = *(const float4*)&T[(size_t)v * CH + c];
        float4 bb = *(const float4*)&bias[c];
        acc.x += dd * sv.x + bb.x;
        acc.y += dd * sv.y + bb.y;
        acc.z += dd * sv.z + bb.z;
        acc.w += dd * sv.w + bb.w;
        if (do_relu) {
            acc.x = fmaxf(acc.x, 0.f); acc.y = fmaxf(acc.y, 0.f);
            acc.z = fmaxf(acc.z, 0.f); acc.w = fmaxf(acc.w, 0.f);
        }
        *(float4*)&out[(size_t)v * CH + c] = acc;
    }
}

// ---- pooling (segmented, batch sorted) + fused classifier -----------------
__global__ __launch_bounds__(128) void k_poolcls(const float* __restrict__ h,
                                                 const int* __restrict__ gstart,
                                                 const float* __restrict__ Wc,
                                                 const float* __restrict__ bc,
                                                 float* __restrict__ out, int OUT) {
    __shared__ float p[CH];
    int g = blockIdx.x;
    int t = threadIdx.x;
    int beg = gstart[g], end = gstart[g + 1];
    float acc = 0.f;
    for (int v = beg; v < end; ++v) acc += h[(size_t)v * CH + t];
    float cnt = fmaxf((float)(end - beg), 1.0f);
    p[t] = acc / cnt;
    __syncthreads();
    if (t < OUT) {
        float s = bc[t];
        for (int k = 0; k < CH; ++k) s += p[k] * Wc[k * OUT + t];
        out[g * OUT + t] = s;
    }
}

extern "C" void kernel_launch(void* const* d_in, const int* in_sizes, int n_in,
                              void* d_out, int out_size, void* d_ws, size_t ws_size,
                              hipStream_t stream) {
    const float* x     = (const float*)d_in[0];
    const int*   eidx  = (const int*)d_in[1];
    const int*   batch = (const int*)d_in[2];
    const float* W0 = (const float*)d_in[3];
    const float* b0 = (const float*)d_in[4];
    const float* W1 = (const float*)d_in[5];
    const float* b1 = (const float*)d_in[6];
    const float* W2 = (const float*)d_in[7];
    const float* b2 = (const float*)d_in[8];
    const float* Wc = (const float*)d_in[9];
    const float* bc = (const float*)d_in[10];
    float* out = (float*)d_out;

    const int n = in_sizes[0] / CH;        // 50000
    const int E = in_sizes[1] / 2;         // 800000
    const int OUT = 12;
    const int G = out_size / OUT;          // 512
    const int* src = eidx;
    const int* dst = eidx + E;

    // ---- workspace carve-up (256B aligned) ----
    char* ws = (char*)d_ws;
    size_t off = 0;
    auto carve = [&](size_t bytes) -> char* {
        off = (off + 255) & ~(size_t)255;
        char* p = ws + off;
        off += bytes;
        return p;
    };
    int*   cnt     = (int*)carve((size_t)2 * n * 4);   // cnt[n] + cursor[n] contiguous
    int*   cursor  = cnt + n;
    int*   rowptr  = (int*)carve((size_t)(n + 1) * 4);
    float* dinv    = (float*)carve((size_t)n * 4);
    int*   csr_src = (int*)carve((size_t)E * 4);
    float* csr_w   = (float*)carve((size_t)E * 4);
    int*   gstart  = (int*)carve((size_t)(G + 1) * 4);
    float* T    = (float*)carve((size_t)n * CH * 4);
    float* bufA = (float*)carve((size_t)n * CH * 4);
    float* bufB = (float*)carve((size_t)n * CH * 4);
    (void)ws_size;

    // ---- zero the accumulators used this launch ----
    hipMemsetAsync(cnt, 0, (size_t)2 * n * 4, stream);

    // ---- graph preprocessing: degree -> dinv -> rowptr -> CSR -> segments --
    k_deg<<<(E + 255) / 256, 256, 0, stream>>>(dst, cnt, E);
    k_dinv<<<(n + 255) / 256, 256, 0, stream>>>(cnt, dinv, n);
    k_scan<<<1, 1024, 0, stream>>>(cnt, rowptr, n);
    k_scatter<<<(E + 255) / 256, 256, 0, stream>>>(src, dst, dinv, rowptr, cursor,
                                                   csr_src, csr_w, E);
    k_bounds<<<(n + 256) / 256, 256, 0, stream>>>(batch, gstart, n, G);

    const int gemm_grid = (n + 63) / 64;
    const int agg_grid  = (n + 3) / 4;

    // ---- layer 0: x -> bufB ----
    k_gemm<<<gemm_grid, 256, 0, stream>>>(x, W0, T, n);
    k_agg<<<agg_grid, 256, 0, stream>>>(T, rowptr, csr_src, csr_w, dinv, b0, bufB, n, 1);
    // ---- layer 1: bufB -> bufA ----
    k_gemm<<<gemm_grid, 256, 0, stream>>>(bufB, W1, T, n);
    k_agg<<<agg_grid, 256, 0, stream>>>(T, rowptr, csr_src, csr_w, dinv, b1, bufA, n, 1);
    // ---- layer 2: bufA -> bufB (no relu) ----
    k_gemm<<<gemm_grid, 256, 0, stream>>>(bufA, W2, T, n);
    k_agg<<<agg_grid, 256, 0, stream>>>(T, rowptr, csr_src, csr_w, dinv, b2, bufB, n, 0);

    // ---- pool + classify (fused) ----
    k_poolcls<<<G, CH, 0, stream>>>(bufB, gstart, Wc, bc, out, OUT);
}

// Round 3
// 349.596 us; speedup vs baseline: 1.6755x; 1.2460x over previous
//
#include <hip/hip_runtime.h>
#include <hip/hip_bf16.h>

// ---------------------------------------------------------------------------
// GCN: 3 x { h = A_norm (x W) + b ; relu } -> mean-pool by graph -> linear
// N=50000 nodes, E=800000 edges, C=128 channels, G=512 graphs, OUT=12
// GEMMs in f32 (vector ALU); the gathered matrix T = X@W is stored bf16 to
// halve gather traffic (accumulation stays f32; final output err ~5e-5 <<
// 3.5e-4 threshold because pooling averages independent per-node quant err).
// CSR built per launch; no float atomics anywhere.
// ---------------------------------------------------------------------------

#define CH 128   // channels (IN == HID)

typedef unsigned int  uint;
typedef unsigned short ushort;

__device__ inline float bflo(uint u) { return __uint_as_float(u << 16); }
__device__ inline float bfhi(uint u) { return __uint_as_float(u & 0xffff0000u); }
__device__ inline ushort f2bf(float f) {           // RNE f32 -> bf16
    uint u = __float_as_uint(f);
    return (ushort)((u + 0x7fffu + ((u >> 16) & 1u)) >> 16);
}

// ---- degree (in-degree, excluding self loop) ------------------------------
__global__ void k_deg(const int* __restrict__ dst, int* __restrict__ cnt, int E) {
    int e = blockIdx.x * blockDim.x + threadIdx.x;
    if (e < E) atomicAdd(&cnt[dst[e]], 1);
}

// ---- dinv[v] = 1/sqrt(indeg+1) --------------------------------------------
__global__ void k_dinv(const int* __restrict__ cnt, float* __restrict__ dinv, int n) {
    int v = blockIdx.x * blockDim.x + threadIdx.x;
    if (v < n) dinv[v] = 1.0f / sqrtf((float)(cnt[v] + 1));
}

// ---- single-block exclusive scan of cnt[0..n) -> rowptr[0..n] -------------
__global__ __launch_bounds__(1024) void k_scan(const int* __restrict__ cnt,
                                               int* __restrict__ rowptr, int n) {
    __shared__ int wave_tot[16];
    __shared__ int chunk_base;
    int tid = threadIdx.x;
    int lane = tid & 63;
    int wid = tid >> 6;
    if (tid == 0) chunk_base = 0;
    __syncthreads();
    const int CHUNK = 4096;  // 1024 threads * 4 elems
    for (int base = 0; base < n; base += CHUNK) {
        int idx0 = base + tid * 4;
        int v0 = (idx0 + 0 < n) ? cnt[idx0 + 0] : 0;
        int v1 = (idx0 + 1 < n) ? cnt[idx0 + 1] : 0;
        int v2 = (idx0 + 2 < n) ? cnt[idx0 + 2] : 0;
        int v3 = (idx0 + 3 < n) ? cnt[idx0 + 3] : 0;
        int local = v0 + v1 + v2 + v3;
        int s = local;
        #pragma unroll
        for (int off = 1; off < 64; off <<= 1) {
            int t = __shfl_up(s, off, 64);
            if (lane >= off) s += t;
        }
        if (lane == 63) wave_tot[wid] = s;
        __syncthreads();
        int wbase = 0;
        for (int w = 0; w < wid; ++w) wbase += wave_tot[w];
        int excl = chunk_base + wbase + (s - local);
        if (idx0 + 0 < n) rowptr[idx0 + 0] = excl;  excl += v0;
        if (idx0 + 1 < n) rowptr[idx0 + 1] = excl;  excl += v1;
        if (idx0 + 2 < n) rowptr[idx0 + 2] = excl;  excl += v2;
        if (idx0 + 3 < n) rowptr[idx0 + 3] = excl;
        __syncthreads();
        if (tid == 1023) chunk_base += wbase + s;
        __syncthreads();
    }
    if (tid == 0) rowptr[n] = chunk_base;
}

// ---- scatter edges into CSR slots: (src, norm-weight) packed 8B -----------
__global__ void k_scatter(const int* __restrict__ src, const int* __restrict__ dst,
                          const float* __restrict__ dinv, const int* __restrict__ rowptr,
                          int* __restrict__ cursor, int2* __restrict__ csr, int E) {
    int e = blockIdx.x * blockDim.x + threadIdx.x;
    if (e >= E) return;
    int s = src[e], d = dst[e];
    int pos = rowptr[d] + atomicAdd(&cursor[d], 1);
    csr[pos] = make_int2(s, __float_as_int(dinv[s] * dinv[d]));
}

// ---- graph segment boundaries: gstart[g] = first v with batch[v] >= g -----
__global__ void k_bounds(const int* __restrict__ batch, int* __restrict__ gstart,
                         int n, int G) {
    int v = blockIdx.x * blockDim.x + threadIdx.x;
    if (v > n) return;
    int prev = (v == 0) ? -1 : batch[v - 1];
    int cur  = (v == n) ? G  : batch[v];
    for (int g = prev + 1; g <= cur; ++g) gstart[g] = v;
}

// ---- GEMM: C[M][128] = A[M][128] @ W[128][128], f32 math, bf16 output -----
__global__ __launch_bounds__(256) void k_gemm(const float* __restrict__ A,
                                              const float* __restrict__ W,
                                              ushort* __restrict__ C, int M) {
    __shared__ float As[64][32];
    __shared__ float Bs[32][128];
    int tid = threadIdx.x;
    int tcol = tid & 31;   // 32 col-groups of 4 cols
    int trow = tid >> 5;   // 8 row-groups; rows trow + i*8
    int row0 = blockIdx.x * 64;
    float acc[8][4] = {};
    for (int kk = 0; kk < CH; kk += 32) {
        #pragma unroll
        for (int l = 0; l < 2; ++l) {
            int idx = tid * 2 + l;          // 0..511  (64x32 = 512 float4)
            int r = idx >> 3;
            int kp = (idx & 7) * 4;
            int grow = row0 + r;
            float4 val = (grow < M) ? *(const float4*)&A[(size_t)grow * CH + kk + kp]
                                    : make_float4(0.f, 0.f, 0.f, 0.f);
            *(float4*)&As[r][kp] = val;
        }
        #pragma unroll
        for (int l = 0; l < 4; ++l) {
            int idx = tid * 4 + l;          // 0..1023 (32x128 = 1024 float4)
            int r = idx >> 5;
            int cp = (idx & 31) * 4;
            *(float4*)&Bs[r][cp] = *(const float4*)&W[(size_t)(kk + r) * CH + cp];
        }
        __syncthreads();
        #pragma unroll
        for (int k = 0; k < 32; ++k) {
            float4 b = *(const float4*)&Bs[k][tcol * 4];
            #pragma unroll
            for (int i = 0; i < 8; ++i) {
                float a = As[trow + i * 8][k];
                acc[i][0] += a * b.x; acc[i][1] += a * b.y;
                acc[i][2] += a * b.z; acc[i][3] += a * b.w;
            }
        }
        __syncthreads();
    }
    #pragma unroll
    for (int i = 0; i < 8; ++i) {
        int grow = row0 + trow + i * 8;
        if (grow < M) {
            ushort4 o;
            o.x = f2bf(acc[i][0]); o.y = f2bf(acc[i][1]);
            o.z = f2bf(acc[i][2]); o.w = f2bf(acc[i][3]);
            *(ushort4*)&C[(size_t)grow * CH + tcol * 4] = o;
        }
    }
}

// ---- aggregation: out[v] = dinv[v]^2*T[v] + sum_in w*T[src] + b (,relu) ---
// One wave per node; 4 edges in flight (16-lane group each, 16B bf16/lane).
__global__ __launch_bounds__(256) void k_agg(const ushort* __restrict__ T,
                                             const int* __restrict__ rowptr,
                                             const int2* __restrict__ csr,
                                             const float* __restrict__ dinv,
                                             const float* __restrict__ bias,
                                             float* __restrict__ out,
                                             int n, int do_relu) {
    int wid = threadIdx.x >> 6;
    int lane = threadIdx.x & 63;
    int v = blockIdx.x * 4 + wid;
    if (v >= n) return;
    int q = lane >> 4;       // quarter-wave 0..3 : edge stream
    int l16 = lane & 15;     // 16 lanes x 8 bf16 = 128 channels
    int c = l16 * 8;
    float acc[8] = {};
    int beg = rowptr[v], end = rowptr[v + 1];
    #pragma unroll 2
    for (int p = beg + q; p < end; p += 4) {
        int2 e = csr[p];                   // uniform within 16-lane group
        int s = e.x;
        float w = __int_as_float(e.y);
        uint4 row = *(const uint4*)&T[(size_t)s * CH + c];
        acc[0] += w * bflo(row.x); acc[1] += w * bfhi(row.x);
        acc[2] += w * bflo(row.y); acc[3] += w * bfhi(row.y);
        acc[4] += w * bflo(row.z); acc[5] += w * bfhi(row.z);
        acc[6] += w * bflo(row.w); acc[7] += w * bfhi(row.w);
    }
    // combine the 4 edge streams (same channels live at lane ^16, ^32)
    #pragma unroll
    for (int j = 0; j < 8; ++j) {
        acc[j] += __shfl_xor(acc[j], 16, 64);
        acc[j] += __shfl_xor(acc[j], 32, 64);
    }
    if (q == 0) {
        float di = dinv[v];
        float dd = di * di;
        uint4 sv = *(const uint4*)&T[(size_t)v * CH + c];
        float s0 = bflo(sv.x), s1 = bfhi(sv.x), s2 = bflo(sv.y), s3 = bfhi(sv.y);
        float s4 = bflo(sv.z), s5 = bfhi(sv.z), s6 = bflo(sv.w), s7 = bfhi(sv.w);
        float4 ba = *(const float4*)&bias[c];
        float4 bb = *(const float4*)&bias[c + 4];
        float o0 = acc[0] + dd * s0 + ba.x;
        float o1 = acc[1] + dd * s1 + ba.y;
        float o2 = acc[2] + dd * s2 + ba.z;
        float o3 = acc[3] + dd * s3 + ba.w;
        float o4 = acc[4] + dd * s4 + bb.x;
        float o5 = acc[5] + dd * s5 + bb.y;
        float o6 = acc[6] + dd * s6 + bb.z;
        float o7 = acc[7] + dd * s7 + bb.w;
        if (do_relu) {
            o0 = fmaxf(o0, 0.f); o1 = fmaxf(o1, 0.f);
            o2 = fmaxf(o2, 0.f); o3 = fmaxf(o3, 0.f);
            o4 = fmaxf(o4, 0.f); o5 = fmaxf(o5, 0.f);
            o6 = fmaxf(o6, 0.f); o7 = fmaxf(o7, 0.f);
        }
        *(float4*)&out[(size_t)v * CH + c]     = make_float4(o0, o1, o2, o3);
        *(float4*)&out[(size_t)v * CH + c + 4] = make_float4(o4, o5, o6, o7);
    }
}

// ---- pooling (segmented, batch sorted) + fused classifier -----------------
__global__ __launch_bounds__(128) void k_poolcls(const float* __restrict__ h,
                                                 const int* __restrict__ gstart,
                                                 const float* __restrict__ Wc,
                                                 const float* __restrict__ bc,
                                                 float* __restrict__ out, int OUT) {
    __shared__ float p[CH];
    int g = blockIdx.x;
    int t = threadIdx.x;
    int beg = gstart[g], end = gstart[g + 1];
    float acc = 0.f;
    for (int v = beg; v < end; ++v) acc += h[(size_t)v * CH + t];
    float cnt = fmaxf((float)(end - beg), 1.0f);
    p[t] = acc / cnt;
    __syncthreads();
    if (t < OUT) {
        float s = bc[t];
        for (int k = 0; k < CH; ++k) s += p[k] * Wc[k * OUT + t];
        out[g * OUT + t] = s;
    }
}

extern "C" void kernel_launch(void* const* d_in, const int* in_sizes, int n_in,
                              void* d_out, int out_size, void* d_ws, size_t ws_size,
                              hipStream_t stream) {
    const float* x     = (const float*)d_in[0];
    const int*   eidx  = (const int*)d_in[1];
    const int*   batch = (const int*)d_in[2];
    const float* W0 = (const float*)d_in[3];
    const float* b0 = (const float*)d_in[4];
    const float* W1 = (const float*)d_in[5];
    const float* b1 = (const float*)d_in[6];
    const float* W2 = (const float*)d_in[7];
    const float* b2 = (const float*)d_in[8];
    const float* Wc = (const float*)d_in[9];
    const float* bc = (const float*)d_in[10];
    float* out = (float*)d_out;

    const int n = in_sizes[0] / CH;        // 50000
    const int E = in_sizes[1] / 2;         // 800000
    const int OUT = 12;
    const int G = out_size / OUT;          // 512
    const int* src = eidx;
    const int* dst = eidx + E;

    // ---- workspace carve-up (256B aligned) ----
    char* ws = (char*)d_ws;
    size_t off = 0;
    auto carve = [&](size_t bytes) -> char* {
        off = (off + 255) & ~(size_t)255;
        char* p = ws + off;
        off += bytes;
        return p;
    };
    int*    cnt    = (int*)carve((size_t)2 * n * 4);   // cnt[n] + cursor[n]
    int*    cursor = cnt + n;
    int*    rowptr = (int*)carve((size_t)(n + 1) * 4);
    float*  dinv   = (float*)carve((size_t)n * 4);
    int2*   csr    = (int2*)carve((size_t)E * 8);
    int*    gstart = (int*)carve((size_t)(G + 1) * 4);
    ushort* T      = (ushort*)carve((size_t)n * CH * 2);   // bf16 gather matrix
    float*  bufA   = (float*)carve((size_t)n * CH * 4);
    float*  bufB   = (float*)carve((size_t)n * CH * 4);
    (void)ws_size;

    hipMemsetAsync(cnt, 0, (size_t)2 * n * 4, stream);

    // ---- graph preprocessing: degree -> dinv -> rowptr -> CSR -> segments --
    k_deg<<<(E + 255) / 256, 256, 0, stream>>>(dst, cnt, E);
    k_dinv<<<(n + 255) / 256, 256, 0, stream>>>(cnt, dinv, n);
    k_scan<<<1, 1024, 0, stream>>>(cnt, rowptr, n);
    k_scatter<<<(E + 255) / 256, 256, 0, stream>>>(src, dst, dinv, rowptr, cursor,
                                                   csr, E);
    k_bounds<<<(n + 256) / 256, 256, 0, stream>>>(batch, gstart, n, G);

    const int gemm_grid = (n + 63) / 64;
    const int agg_grid  = (n + 3) / 4;

    // ---- layer 0: x -> bufB ----
    k_gemm<<<gemm_grid, 256, 0, stream>>>(x, W0, T, n);
    k_agg<<<agg_grid, 256, 0, stream>>>(T, rowptr, csr, dinv, b0, bufB, n, 1);
    // ---- layer 1: bufB -> bufA ----
    k_gemm<<<gemm_grid, 256, 0, stream>>>(bufB, W1, T, n);
    k_agg<<<agg_grid, 256, 0, stream>>>(T, rowptr, csr, dinv, b1, bufA, n, 1);
    // ---- layer 2: bufA -> bufB (no relu) ----
    k_gemm<<<gemm_grid, 256, 0, stream>>>(bufA, W2, T, n);
    k_agg<<<agg_grid, 256, 0, stream>>>(T, rowptr, csr, dinv, b2, bufB, n, 0);

    // ---- pool + classify (fused) ----
    k_poolcls<<<G, CH, 0, stream>>>(bufB, gstart, Wc, bc, out, OUT);
}